// Round 1
// baseline (261.978 us; speedup 1.0000x reference)
//
#include <hip/hip_runtime.h>
#include <stdint.h>

// R5: NCONF=8192, NT=64, NX=64
// out0[i,t,j] = sum_y phi[i,t,y] * W[(y+T0)&63, (j+T0)&63] + b[(j+T0)&63]
// out1[i]     = 64 * log|det W|
//
// Changes vs R4 (82us equiv_main @ 2.5TB/s, latency-bound):
//  - T0 precomputed in fused prep kernel -> main kernel has no
//    load->argmin->load serial chain; all loads issue up front.
//  - 2 configs per wave, pipelined (cfgB loads hide under cfgA compute).
//    __launch_bounds__(256,2) caps VGPR at 256 (2 waves/SIMD, ~128KB/CU in
//    flight >> ~9KB needed for 6.3TB/s).
//  - LU moved to prep kernel (overlaps t0 blocks + main ramp) and rewritten
//    non-pivoted: uniform-k v_readlane instead of runtime-p bpermute chains;
//    pivot-row self-zeroing (m = piv/piv = 1) removes the used-mask.
//    Pivot order does not change |det|; W = I + 0.1*N(0,1) is safe no-pivot.
//  - Non-temporal stores for out0 (writes are stream-once; keep L3 for phi).

typedef _Float16 half8v __attribute__((ext_vector_type(8)));
typedef float float4v __attribute__((ext_vector_type(4)));

__device__ __forceinline__ float rdlane_f(float v, int l) {
  return __int_as_float(__builtin_amdgcn_readlane(__float_as_int(v), l));
}

// prep: bid<64 -> wt2 table; bid==64 -> no-pivot LU logdet; bid>=65 -> T0
// WT2[s][j][y] = (f16) W[(y+s)&63][(j+s)&63]   (y contiguous)
__global__ __launch_bounds__(256) void prep(
    const float* __restrict__ phi, const float* __restrict__ W,
    _Float16* __restrict__ wt2, int* __restrict__ t0arr, const int t0stride,
    float* __restrict__ out) {
  const int bid = blockIdx.x;
  const int tid = threadIdx.x;
  if (bid < 64) {
    const int s = bid;
#pragma unroll
    for (int it = 0; it < 16; ++it) {
      int flat = it * 256 + tid;
      int j = flat >> 6, y = flat & 63;
      wt2[(size_t)s * 4096 + flat] =
          (_Float16)W[((y + s) & 63) * 64 + ((j + s) & 63)];
    }
    return;
  }
  if (bid == 64) {
    // ---- register LU, no pivoting, lane t owns row t, shift-down keeps the
    // active pivot column at r[0]. At step k: lane k computes m=1 and zeroes
    // its own row (reads happen before writes in lockstep), lanes t<k have
    // zero rows -> m=0 no-op, lanes t>k eliminate normally. det = prod(piv).
    if (tid >= 64) return;
    const int t = tid;
    float r[64];
#pragma unroll
    for (int i = 0; i < 64; ++i) r[i] = W[t * 64 + i];
    float ldsum = 0.f;
#pragma unroll 1
    for (int k = 0; k < 64; ++k) {
      float v0 = r[0];
      float piv = rdlane_f(v0, k);  // uniform k -> v_readlane, no LDS pipe
      ldsum += logf(fabsf(piv));
      float mf = v0 / piv;
#pragma unroll
      for (int i = 1; i < 64; ++i) {
        float pe = rdlane_f(r[i], k);
        r[i - 1] = r[i] - mf * pe;
      }
      r[63] = 0.f;
    }
    float ld = 64.0f * ldsum;  // NT * logabsdet
    float* outLD = out + (size_t)8192 * 4096;
#pragma unroll
    for (int it = 0; it < 128; ++it) outLD[it * 64 + t] = ld;
    return;
  }
  // ---- T0 per config: 4 configs/block, 1 wave each. lane = t. ----
  const int wave = tid >> 6, lane = tid & 63;
  const int cfg = (bid - 65) * 4 + wave;
  const float2 v = *(const float2*)&phi[(size_t)cfg * 4096 + lane * 64];
  unsigned long long k0 =
      (((unsigned long long)__float_as_uint(fabsf(v.x))) << 6) |
      (unsigned long long)lane;
  unsigned long long k1 =
      (((unsigned long long)__float_as_uint(fabsf(v.y))) << 6) |
      (unsigned long long)lane;
#pragma unroll
  for (int s = 1; s < 64; s <<= 1) {
    unsigned long long o0 = __shfl_xor(k0, s);
    unsigned long long o1 = __shfl_xor(k1, s);
    k0 = o0 < k0 ? o0 : k0;
    k1 = o1 < k1 ? o1 : k1;
  }
  if (lane == 0) {
    int t0i = (int)(k0 & 63ull), t1i = (int)(k1 & 63ull);
    t0arr[(size_t)cfg * t0stride] = (t0i > t1i) ? t1i : t0i;
  }
}

__device__ __forceinline__ void gemm_one(const float4v (&f)[4][2][2],
                                         const half8v (&Bf)[2][4],
                                         const float (&bias)[4], const int m,
                                         const int q, float* __restrict__ op) {
  half8v Af[4][2];
#pragma unroll
  for (int mt = 0; mt < 4; ++mt)
#pragma unroll
    for (int ks = 0; ks < 2; ++ks) {
      half8v h;
#pragma unroll
      for (int kk = 0; kk < 4; ++kk) {
        h[kk] = (_Float16)f[mt][ks][0][kk];
        h[kk + 4] = (_Float16)f[mt][ks][1][kk];
      }
      Af[mt][ks] = h;
    }
  float4v acc[4][4];
#pragma unroll
  for (int mt = 0; mt < 4; ++mt)
#pragma unroll
    for (int nt = 0; nt < 4; ++nt) acc[mt][nt] = (float4v)(0.f);
#pragma unroll
  for (int ks = 0; ks < 2; ++ks)
#pragma unroll
    for (int mt = 0; mt < 4; ++mt)
#pragma unroll
      for (int nt = 0; nt < 4; ++nt)
        acc[mt][nt] = __builtin_amdgcn_mfma_f32_16x16x32_f16(
            Af[mt][ks], Bf[ks][nt], acc[mt][nt], 0, 0, 0);
  // C layout: col = nt*16 + m, row = mt*16 + q*4 + r
#pragma unroll
  for (int mt = 0; mt < 4; ++mt)
#pragma unroll
    for (int nt = 0; nt < 4; ++nt)
#pragma unroll
      for (int r = 0; r < 4; ++r)
        __builtin_nontemporal_store(
            acc[mt][nt][r] + bias[nt],
            &op[(mt * 16 + q * 4 + r) * 64 + nt * 16 + m]);
}

__global__ __launch_bounds__(256, 2) void equiv_main(
    const float* __restrict__ phi, const float* __restrict__ b,
    const _Float16* __restrict__ wt2, const int* __restrict__ t0arr,
    const int t0stride, float* __restrict__ out) {
  const int lane = threadIdx.x & 63;
  const int wave = threadIdx.x >> 6;
  const int wid = blockIdx.x * 4 + wave;
  const int cfgA = wid * 2, cfgB = wid * 2 + 1;
  const int m = lane & 15;  // MFMA row/col within tile
  const int q = lane >> 4;  // quad: k-chunk selector

  // T0 broadcast loads first (they gate the wt2 loads)
  int T0A = t0arr[(size_t)cfgA * t0stride];
  int T0B = t0arr[(size_t)cfgB * t0stride];

  // ---- all phi loads issue up front: 32 dwordx4 in flight per wave ----
  const float* phA = phi + (size_t)cfgA * 4096;
  const float* phB = phi + (size_t)cfgB * 4096;
  float4v fA[4][2][2], fB[4][2][2];
#pragma unroll
  for (int mt = 0; mt < 4; ++mt)
#pragma unroll
    for (int ks = 0; ks < 2; ++ks)
#pragma unroll
      for (int h = 0; h < 2; ++h) {
        fA[mt][ks][h] =
            *(const float4v*)&phA[(mt * 16 + m) * 64 + ks * 32 + q * 8 + h * 4];
        fB[mt][ks][h] =
            *(const float4v*)&phB[(mt * 16 + m) * 64 + ks * 32 + q * 8 + h * 4];
      }

  T0A = __builtin_amdgcn_readfirstlane(T0A);
  T0B = __builtin_amdgcn_readfirstlane(T0B);

  // ---- B fragments from L2-resident WT2 ----
  const _Float16* wtA = wt2 + (size_t)T0A * 4096;
  const _Float16* wtB = wt2 + (size_t)T0B * 4096;
  half8v BfA[2][4], BfB[2][4];
#pragma unroll
  for (int ks = 0; ks < 2; ++ks)
#pragma unroll
    for (int nt = 0; nt < 4; ++nt) {
      BfA[ks][nt] = *(const half8v*)&wtA[(nt * 16 + m) * 64 + ks * 32 + q * 8];
      BfB[ks][nt] = *(const half8v*)&wtB[(nt * 16 + m) * 64 + ks * 32 + q * 8];
    }
  float biasA[4], biasB[4];
#pragma unroll
  for (int nt = 0; nt < 4; ++nt) {
    biasA[nt] = b[(nt * 16 + m + T0A) & 63];
    biasB[nt] = b[(nt * 16 + m + T0B) & 63];
  }

  // compute A while B's loads are still in flight, then B
  gemm_one(fA, BfA, biasA, m, q, out + (size_t)cfgA * 4096);
  gemm_one(fB, BfB, biasB, m, q, out + (size_t)cfgB * 4096);
}

extern "C" void kernel_launch(void* const* d_in, const int* in_sizes, int n_in,
                              void* d_out, int out_size, void* d_ws,
                              size_t ws_size, hipStream_t stream) {
  const float* phi = (const float*)d_in[0];
  const float* W = (const float*)d_in[1];
  const float* b = (const float*)d_in[2];
  float* out = (float*)d_out;
  _Float16* wt2 = (_Float16*)d_ws;  // 64 shifts x 64x64 f16 = 512 KB

  int* t0arr;
  int t0stride;
  if (ws_size >= (size_t)(512 * 1024 + 32 * 1024)) {
    t0arr = (int*)((char*)d_ws + 512 * 1024);  // 8192 ints
    t0stride = 1;
  } else {
    // fallback: stash T0[cfg] (int bits) at out[cfg*4096]; only the owning
    // wave reads it, before that wave's own stores overwrite the region.
    t0arr = (int*)d_out;
    t0stride = 4096;
  }

  prep<<<dim3(65 + 2048), dim3(256), 0, stream>>>(phi, W, wt2, t0arr, t0stride,
                                                  out);
  equiv_main<<<dim3(1024), dim3(256), 0, stream>>>(phi, b, wt2, t0arr, t0stride,
                                                   out);
}

// Round 2
// 242.919 us; speedup vs baseline: 1.0785x; 1.0785x over previous
//
#include <hip/hip_runtime.h>
#include <stdint.h>

// R6: NCONF=8192, NT=64, NX=64
// out0[i,t,j] = sum_y phi[i,t,y] * W[(y+T0)&63, (j+T0)&63] + b[(j+T0)&63]
// out1[i]     = 64 * log|det W|
//
// Theory R6: R4 and R5 both landed at 82us with identical *transaction*
// structure (strided 16B-granular loads: 32 lines/instr at 50% use; scattered
// dword stores: 4x64B segments/instr) despite different byte counts ->
// transaction-rate bound, not byte bound. Fix: every global access becomes a
// full-wave contiguous 1KB dwordx4 (the 6.7TB/s fill-kernel pattern):
//  - phi: 16 contiguous global_load_dwordx4 per wave -> cvt f16 -> wave-
//    private LDS (XOR-swizzled, 2-way max) -> ds_read_b128 MFMA fragments.
//  - T0 argmin from the contiguous f32 regs (lanes 0/16/32/48 own cols 0..3),
//    exact f32 key semantics as before. T0-prep blocks deleted (R5 regression).
//  - epilogue: acc -> LDS (swizzled, 2-way) -> ds_read_b128 -> 16 contiguous
//    nontemporal store_dwordx4 per cfg (full lines: no NT amplification, and
//    out bypasses L3 so phi stays resident).
//  - LU (no-pivot, readlane) in main block 0; wt2 table prep is 64 blocks.

typedef _Float16 half8v __attribute__((ext_vector_type(8)));
typedef _Float16 half4v __attribute__((ext_vector_type(4)));
typedef float float4v __attribute__((ext_vector_type(4)));

__device__ __forceinline__ float rdlane_f(float v, int l) {
  return __int_as_float(__builtin_amdgcn_readlane(__float_as_int(v), l));
}

// WT2[s][j][y] = (f16) W[(y+s)&63][(j+s)&63]   (y contiguous)
__global__ __launch_bounds__(256) void wt2_prep(const float* __restrict__ W,
                                                _Float16* __restrict__ wt2) {
  const int s = blockIdx.x;
  const int tid = threadIdx.x;
#pragma unroll
  for (int it = 0; it < 16; ++it) {
    int flat = it * 256 + tid;
    int j = flat >> 6, y = flat & 63;
    wt2[(size_t)s * 4096 + flat] =
        (_Float16)W[((y + s) & 63) * 64 + ((j + s) & 63)];
  }
}

__global__ __launch_bounds__(256) void equiv_main(
    const float* __restrict__ phi, const float* __restrict__ W,
    const float* __restrict__ b, const _Float16* __restrict__ wt2,
    float* __restrict__ out) {
  // 8KB per wave, reused: f16 phi tile (staging) then f32 store stripes.
  __shared__ __align__(16) _Float16 smem[4][4096];
  const int lane = threadIdx.x & 63;
  const int wave = threadIdx.x >> 6;

  if (blockIdx.x == 0) {
    // ---- register LU, no pivoting (W = I + 0.1*N(0,1) is safe): lane t owns
    // row t; shift-down keeps pivot col at r[0]; uniform-k readlane broadcast.
    // Step k: lane k gets m=1 and self-zeroes; lanes t<k are zero rows (m=0).
    if (threadIdx.x >= 64) return;
    const int t = lane;
    float r[64];
#pragma unroll
    for (int i = 0; i < 64; ++i) r[i] = W[t * 64 + i];
    float ldsum = 0.f;
#pragma unroll 1
    for (int k = 0; k < 64; ++k) {
      float v0 = r[0];
      float piv = rdlane_f(v0, k);
      ldsum += logf(fabsf(piv));
      float mf = v0 / piv;
#pragma unroll
      for (int i = 1; i < 64; ++i) {
        float pe = rdlane_f(r[i], k);
        r[i - 1] = r[i] - mf * pe;
      }
      r[63] = 0.f;
    }
    float ld = 64.0f * ldsum;  // NT * logabsdet
    float* outLD = out + (size_t)8192 * 4096;
#pragma unroll
    for (int it = 0; it < 128; ++it) outLD[it * 64 + t] = ld;
    return;
  }

  const int cfg = ((int)blockIdx.x - 1) * 4 + wave;
  const int m = lane & 15;  // MFMA row/col within 16-tile
  const int q = lane >> 4;  // quad

  // ---- 16 fully-contiguous dwordx4 loads: lane*16B + i*1KB ----
  // fr[i] = phi[cfg][row = i*4 + (lane>>4)][col = (lane&15)*4 .. +3]
  const float* ph = phi + (size_t)cfg * 4096;
  float4v fr[16];
#pragma unroll
  for (int i = 0; i < 16; ++i) fr[i] = *(const float4v*)&ph[i * 256 + lane * 4];

  // ---- T0 argmin (exact f32 keys): cols 0,1 live in lanes with m==0 ----
  unsigned long long k0 = ~0ull, k1 = ~0ull;
  if (m == 0) {
#pragma unroll
    for (int i = 0; i < 16; ++i) {
      unsigned long long tt = (unsigned long long)(i * 4 + q);
      unsigned long long c0 =
          (((unsigned long long)__float_as_uint(fabsf(fr[i].x))) << 6) | tt;
      unsigned long long c1 =
          (((unsigned long long)__float_as_uint(fabsf(fr[i].y))) << 6) | tt;
      k0 = c0 < k0 ? c0 : k0;
      k1 = c1 < k1 ? c1 : k1;
    }
  }
#pragma unroll
  for (int s = 1; s < 64; s <<= 1) {
    unsigned long long o0 = __shfl_xor(k0, s);
    unsigned long long o1 = __shfl_xor(k1, s);
    k0 = o0 < k0 ? o0 : k0;
    k1 = o1 < k1 ? o1 : k1;
  }
  const int t0i = (int)(k0 & 63ull), t1i = (int)(k1 & 63ull);
  const int T0 = (t0i > t1i) ? t1i : t0i;

  // ---- B fragments from L2-resident WT2[T0] (16B aligned, as before) ----
  const _Float16* wt = wt2 + (size_t)T0 * 4096;
  half8v Bf[2][4];
#pragma unroll
  for (int ks = 0; ks < 2; ++ks)
#pragma unroll
    for (int nt = 0; nt < 4; ++nt)
      Bf[ks][nt] = *(const half8v*)&wt[(nt * 16 + m) * 64 + ks * 32 + q * 8];
  float bias[4];
#pragma unroll
  for (int nt = 0; nt < 4; ++nt) bias[nt] = b[(nt * 16 + m + T0) & 63];

  // ---- stage phi -> f16 LDS, XOR-swizzled (dword-col ^= (row&7)<<2) ----
  // f16 row = 32 dwords; float4 -> half4 (2 dwords), b64 write, 2-way max.
  _Float16* sw = smem[wave];
#pragma unroll
  for (int i = 0; i < 16; ++i) {
    int row = i * 4 + q;
    int dwc = (m * 2) ^ ((row & 7) << 2);
    half4v h;
    h[0] = (_Float16)fr[i][0];
    h[1] = (_Float16)fr[i][1];
    h[2] = (_Float16)fr[i][2];
    h[3] = (_Float16)fr[i][3];
    *(half4v*)&sw[row * 64 + dwc * 2] = h;
  }
  asm volatile("s_waitcnt lgkmcnt(0)" ::: "memory");
  __builtin_amdgcn_sched_barrier(0);

  // ---- A fragments: ds_read_b128, row = mt*16+m, k-dwords (ks*16+q*4)^swz ----
  half8v Af[4][2];
#pragma unroll
  for (int mt = 0; mt < 4; ++mt)
#pragma unroll
    for (int ks = 0; ks < 2; ++ks) {
      int row = mt * 16 + m;
      int dwc = (ks * 16 + q * 4) ^ ((row & 7) << 2);
      Af[mt][ks] = *(const half8v*)&sw[row * 64 + dwc * 2];
    }

  // ---- 32 MFMAs ----
  float4v acc[4][4];
#pragma unroll
  for (int mt = 0; mt < 4; ++mt)
#pragma unroll
    for (int nt = 0; nt < 4; ++nt) acc[mt][nt] = (float4v)(0.f);
#pragma unroll
  for (int ks = 0; ks < 2; ++ks)
#pragma unroll
    for (int mt = 0; mt < 4; ++mt)
#pragma unroll
      for (int nt = 0; nt < 4; ++nt)
        acc[mt][nt] = __builtin_amdgcn_mfma_f32_16x16x32_f16(
            Af[mt][ks], Bf[ks][nt], acc[mt][nt], 0, 0, 0);

  // ---- epilogue: two 32-row f32 stripes through LDS -> contiguous NT x4 ----
  // acc[mt][nt][r] = out[row = mt*16 + q*4 + r][col = nt*16 + m]
  float* fsm = (float*)smem[wave];  // 2048 f32 = 32 rows x 64
  float* op = out + (size_t)cfg * 4096;
#pragma unroll
  for (int s = 0; s < 2; ++s) {
    asm volatile("s_waitcnt lgkmcnt(0)" ::: "memory");  // stripe reuse guard
    __builtin_amdgcn_sched_barrier(0);
#pragma unroll
    for (int mh = 0; mh < 2; ++mh) {
      int mt = s * 2 + mh;
#pragma unroll
      for (int nt = 0; nt < 4; ++nt)
#pragma unroll
        for (int r = 0; r < 4; ++r) {
          int lrow = mh * 16 + q * 4 + r;
          int dwc = (nt * 16 + m) ^ ((lrow & 7) << 2);
          fsm[lrow * 64 + dwc] = acc[mt][nt][r] + bias[nt];
        }
    }
    asm volatile("s_waitcnt lgkmcnt(0)" ::: "memory");
    __builtin_amdgcn_sched_barrier(0);
#pragma unroll
    for (int j = 0; j < 8; ++j) {
      int flat = j * 256 + lane * 4;
      int lrow = flat >> 6;
      int dwc = (flat & 63) ^ ((lrow & 7) << 2);
      float4v v = *(const float4v*)&fsm[lrow * 64 + dwc];
      __builtin_nontemporal_store(v, (float4v*)&op[s * 2048 + flat]);
    }
  }
}

extern "C" void kernel_launch(void* const* d_in, const int* in_sizes, int n_in,
                              void* d_out, int out_size, void* d_ws,
                              size_t ws_size, hipStream_t stream) {
  const float* phi = (const float*)d_in[0];
  const float* W = (const float*)d_in[1];
  const float* b = (const float*)d_in[2];
  float* out = (float*)d_out;
  _Float16* wt2 = (_Float16*)d_ws;  // 64 shifts x 64x64 f16 = 512 KB

  wt2_prep<<<dim3(64), dim3(256), 0, stream>>>(W, wt2);
  equiv_main<<<dim3(2049), dim3(256), 0, stream>>>(phi, W, b, wt2, out);
}